// Round 15
// baseline (418.732 us; speedup 1.0000x reference)
//
#include <hip/hip_runtime.h>
#include <math.h>

#define BN_EPS 1e-5f
#define BCAP 12544   // per-bucket edge capacity (expected ~6250 for uniform dsts)

using bf16x8 = __attribute__((ext_vector_type(8))) short;
using f32x4  = __attribute__((ext_vector_type(4))) float;

// ---------------- bf16 helpers (RNE) ----------------

__device__ __forceinline__ float bf2f(unsigned short u) {
    union { unsigned int i; float f; } v; v.i = ((unsigned int)u) << 16; return v.f;
}
__device__ __forceinline__ unsigned short f2bf(float f) {
    union { float f; unsigned int i; } v; v.f = f;
    unsigned int lsb = (v.i >> 16) & 1u;
    v.i += 0x7fffu + lsb;
    return (unsigned short)(v.i >> 16);
}
__device__ __forceinline__ unsigned int pack2bf(float a, float b) {
    return (unsigned int)f2bf(a) | ((unsigned int)f2bf(b) << 16);
}

// ---------------- CSR build (2-kernel hierarchical) ----------------

// Phase A: append packed (src | dstLocal<<17) into fixed-capacity bucket regions.
__global__ __launch_bounds__(256)
void bucketA_kernel(const int* __restrict__ srcv, const int* __restrict__ dstv,
                    int* __restrict__ cursor, int* __restrict__ bkt, int E) {
    __shared__ int hist[256], base[256], lcur[256];
    __shared__ int2 stage[4096];
    int tid = threadIdx.x;
    hist[tid] = 0; lcur[tid] = 0;
    __syncthreads();
    int e0 = blockIdx.x * 4096;
    int nmax = E - e0; if (nmax > 4096) nmax = 4096;

    #pragma unroll
    for (int u = 0; u < 16; ++u) {
        int idx = u * 256 + tid;
        if (idx < nmax) {
            int e = e0 + idx;
            int d = dstv[e], s = srcv[e];
            stage[idx] = make_int2(d, s);
            atomicAdd(&hist[d >> 9], 1);
        }
    }
    __syncthreads();
    if (hist[tid] > 0) base[tid] = atomicAdd(&cursor[tid], hist[tid]);
    __syncthreads();
    #pragma unroll
    for (int u = 0; u < 16; ++u) {
        int idx = u * 256 + tid;
        if (idx < nmax) {
            int2 ds = stage[idx];
            int b = ds.x >> 9;
            int dl = ds.x & 511;
            int slot = base[b] + atomicAdd(&lcur[b], 1);
            if (slot < BCAP)  // never triggers for uniform dsts; OOB guard only
                bkt[b * BCAP + slot] = ds.y | (dl << 17);
        }
    }
}

// 1 block: exclusive scan of cursor (=bucket counts) -> bucketBase; row_ptr[Nn]=E
__global__ void scanB_kernel(const int* __restrict__ cursor, int* __restrict__ bucketBase,
                             int* __restrict__ row_ptr, int E, int Nn) {
    __shared__ int s[256];
    int t = threadIdx.x;
    int v = cursor[t];
    s[t] = v;
    __syncthreads();
    for (int off = 1; off < 256; off <<= 1) {
        int add = (t >= off) ? s[t - off] : 0;
        __syncthreads();
        s[t] += add;
        __syncthreads();
    }
    bucketBase[t] = s[t] - v;
    if (t == 0) row_ptr[Nn] = E;
}

// Phase B: one block per bucket — degrees/dinv/row_ptr in LDS, reorder col into
// block-local CSR window; also graph boundaries (batch sorted).
__global__ __launch_bounds__(256)
void orderB_kernel(const int* __restrict__ bkt, const int* __restrict__ cursor,
                   const int* __restrict__ bucketBase,
                   int* __restrict__ row_ptr, float* __restrict__ dinv, int* __restrict__ col,
                   const int* __restrict__ batch, int* __restrict__ start,
                   int Nn, int G) {
    __shared__ int hist[512];
    __shared__ int scan_s[256];
    int b = blockIdx.x;
    int lo = b << 9;
    if (lo >= Nn) return;
    int hi = lo + 512; if (hi > Nn) hi = Nn;
    int cnt = cursor[b];
    int g0 = b * BCAP;             // bucket segment [g0, g0+cnt)
    int c0 = bucketBase[b];        // CSR offset of this bucket
    int tid = threadIdx.x;
    hist[tid] = 0; hist[tid + 256] = 0;
    __syncthreads();
    for (int i = tid; i < cnt; i += 256)
        atomicAdd(&hist[(((unsigned int)bkt[g0 + i]) >> 17) & 511], 1);
    __syncthreads();
    int a0 = hist[2 * tid], a1 = hist[2 * tid + 1];
    int n0 = lo + 2 * tid, n1 = n0 + 1;
    if (n0 < Nn) dinv[n0] = rsqrtf((float)a0 + 1.0f);
    if (n1 < Nn) dinv[n1] = rsqrtf((float)a1 + 1.0f);
    int pairsum = a0 + a1;
    scan_s[tid] = pairsum;
    __syncthreads();
    for (int off = 1; off < 256; off <<= 1) {
        int add = (tid >= off) ? scan_s[tid - off] : 0;
        __syncthreads();
        scan_s[tid] += add;
        __syncthreads();
    }
    int excl = scan_s[tid] - pairsum;
    __syncthreads();
    if (n0 < Nn) row_ptr[n0] = c0 + excl;
    if (n1 < Nn) row_ptr[n1] = c0 + excl + a0;
    hist[2 * tid] = excl;
    hist[2 * tid + 1] = excl + a0;
    __syncthreads();
    for (int i = tid; i < cnt; i += 256) {
        int en = bkt[g0 + i];
        int dl = (((unsigned int)en) >> 17) & 511;
        int slot = atomicAdd(&hist[dl], 1);
        col[c0 + slot] = en & 0x1ffff;
    }
    for (int i = lo + tid; i < hi; i += 256) {
        int bb = batch[i];
        if (i == 0) {
            for (int g = 0; g <= bb; ++g) start[g] = 0;
        } else {
            int p = batch[i - 1];
            for (int g = p + 1; g <= bb; ++g) start[g] = i;
        }
        if (i == Nn - 1) {
            for (int g = bb + 1; g <= G; ++g) start[g] = Nn;
        }
    }
}

// ---------------- weight f32 -> bf16 conversion ----------------

__global__ void convw_kernel(const float* __restrict__ W1, const float* __restrict__ W2,
                             const float* __restrict__ W3,
                             unsigned short* __restrict__ w1b, unsigned short* __restrict__ w2b,
                             unsigned short* __restrict__ w3b) {
    int i = blockIdx.x * 256 + threadIdx.x;
    if (i < 128 * 128) w1b[i] = f2bf(W1[i]);
    if (i < 128 * 64)  w2b[i] = f2bf(W2[i]);
    if (i < 64 * 64)   w3b[i] = f2bf(W3[i]);
}

// ---------------- MFMA GEMM: C[M,N](bf16) = dinv[row] * (A[M,K] @ Wb[K,N]) ----------------

template<int K, int N, bool AF32>
__global__ __launch_bounds__(256)
void gemm_mfma(const void* __restrict__ Ap, const unsigned short* __restrict__ Wb,
               const float* __restrict__ dinv, unsigned short* __restrict__ C, int M) {
    constexpr int KF = K / 32;
    constexpr int NF = N / 16;
    __shared__ __align__(16) unsigned short ldsW[KF * NF * 64 * 8];

    for (int c = threadIdx.x; c < K * N / 8; c += 256) {
        int e0 = c * 8;
        int k = e0 / N, n0 = e0 % N;
        uint4 v = *(const uint4*)&Wb[e0];
        unsigned short w[8];
        w[0] = (unsigned short)(v.x & 0xffff); w[1] = (unsigned short)(v.x >> 16);
        w[2] = (unsigned short)(v.y & 0xffff); w[3] = (unsigned short)(v.y >> 16);
        w[4] = (unsigned short)(v.z & 0xffff); w[5] = (unsigned short)(v.z >> 16);
        w[6] = (unsigned short)(v.w & 0xffff); w[7] = (unsigned short)(v.w >> 16);
        int j    = k & 7;
        int lhi  = ((k & 31) >> 3) << 4;
        int fbase = (k >> 5) * NF;
        #pragma unroll
        for (int u = 0; u < 8; ++u) {
            int n = n0 + u;
            int f = fbase + (n >> 4);
            int l = lhi | (n & 15);
            ldsW[(f * 64 + l) * 8 + j] = w[u];
        }
    }
    __syncthreads();

    const int wave = threadIdx.x >> 6;
    const int lane = threadIdx.x & 63;
    const int r0   = blockIdx.x * 64 + wave * 16;

    int arow = r0 + (lane & 15);
    if (arow >= M) arow = M - 1;
    const int kc0 = (lane >> 4) * 8;
    bf16x8 af[KF];
    #pragma unroll
    for (int k = 0; k < KF; ++k) {
        if constexpr (AF32) {
            const float* A = (const float*)Ap;
            const float4* p = (const float4*)&A[(size_t)arow * K + k * 32 + kc0];
            float4 u0 = p[0], u1 = p[1];
            unsigned int q0 = pack2bf(u0.x, u0.y), q1 = pack2bf(u0.z, u0.w);
            unsigned int q2 = pack2bf(u1.x, u1.y), q3 = pack2bf(u1.z, u1.w);
            bf16x8 a;
            a[0] = (short)(q0 & 0xffff); a[1] = (short)(q0 >> 16);
            a[2] = (short)(q1 & 0xffff); a[3] = (short)(q1 >> 16);
            a[4] = (short)(q2 & 0xffff); a[5] = (short)(q2 >> 16);
            a[6] = (short)(q3 & 0xffff); a[7] = (short)(q3 >> 16);
            af[k] = a;
        } else {
            const unsigned short* A = (const unsigned short*)Ap;
            af[k] = *(const bf16x8*)&A[(size_t)arow * K + k * 32 + kc0];
        }
    }

    const int colb = lane & 15;
    const int rsub = (lane >> 4) * 4;
    float dv[4];
    #pragma unroll
    for (int j = 0; j < 4; ++j) {
        int row = r0 + rsub + j;
        dv[j] = (row < M) ? dinv[row] : 0.0f;
    }
    #pragma unroll
    for (int n = 0; n < NF; ++n) {
        f32x4 acc = {0.f, 0.f, 0.f, 0.f};
        #pragma unroll
        for (int k = 0; k < KF; ++k) {
            bf16x8 bf = *(const bf16x8*)&ldsW[((k * NF + n) * 64 + lane) * 8];
            acc = __builtin_amdgcn_mfma_f32_16x16x32_bf16(af[k], bf, acc, 0, 0, 0);
        }
        int col = n * 16 + colb;
        #pragma unroll
        for (int j = 0; j < 4; ++j) {
            int row = r0 + rsub + j;
            if (row < M) C[(size_t)row * N + col] = f2bf(acc[j] * dv[j]);
        }
    }
}

// ---------------- fused gather + bias + BN + ReLU (dual-edge half-wave) ----------------
// out[i] = relu(BN( dinv[i] * (sum_{s in N(i)} t'[s] + t'[i]) + bias ))
// lanes 0-31: even edge of pair; lanes 32-63: odd edge. Combine via shfl_xor(32).

__global__ __launch_bounds__(256)
void gcn_gather128(const unsigned short* __restrict__ t, unsigned short* __restrict__ out,
                   const int* __restrict__ row_ptr, const int* __restrict__ col,
                   const float* __restrict__ dinv,
                   const float* __restrict__ bias,
                   const float* __restrict__ gam, const float* __restrict__ bet,
                   const float* __restrict__ mu,  const float* __restrict__ var,
                   int Nn) {
    int node = (int)((blockIdx.x * 256 + threadIdx.x) >> 6);
    int lane = threadIdx.x & 63;
    if (node >= Nn) return;
    int half = lane >> 5;
    int l    = lane & 31;          // channels 4l..4l+3 via uint2
    int b0 = row_ptr[node], b1 = row_ptr[node + 1];
    float di = dinv[node];
    const uint2* tu2 = (const uint2*)t;   // row = 32 uint2

    float a0 = 0.f, a1 = 0.f, a2 = 0.f, a3 = 0.f;
    int e = b0;
    for (; e + 16 <= b1; e += 16) {
        int cc[8]; uint2 f[8];
        #pragma unroll
        for (int u = 0; u < 8; ++u) cc[u] = col[e + 2 * u + half];
        #pragma unroll
        for (int u = 0; u < 8; ++u) f[u] = tu2[(size_t)cc[u] * 32 + l];
        #pragma unroll
        for (int u = 0; u < 8; ++u) {
            a0 += bf2f((unsigned short)(f[u].x & 0xffff));
            a1 += bf2f((unsigned short)(f[u].x >> 16));
            a2 += bf2f((unsigned short)(f[u].y & 0xffff));
            a3 += bf2f((unsigned short)(f[u].y >> 16));
        }
    }
    for (; e + 2 <= b1; e += 2) {
        int c = col[e + half];
        uint2 f = tu2[(size_t)c * 32 + l];
        a0 += bf2f((unsigned short)(f.x & 0xffff));
        a1 += bf2f((unsigned short)(f.x >> 16));
        a2 += bf2f((unsigned short)(f.y & 0xffff));
        a3 += bf2f((unsigned short)(f.y >> 16));
    }
    if (e < b1 && half == 0) {
        int c = col[e];
        uint2 f = tu2[(size_t)c * 32 + l];
        a0 += bf2f((unsigned short)(f.x & 0xffff));
        a1 += bf2f((unsigned short)(f.x >> 16));
        a2 += bf2f((unsigned short)(f.y & 0xffff));
        a3 += bf2f((unsigned short)(f.y >> 16));
    }
    a0 += __shfl_xor(a0, 32);
    a1 += __shfl_xor(a1, 32);
    a2 += __shfl_xor(a2, 32);
    a3 += __shfl_xor(a3, 32);

    if (half == 0) {
        uint2 tv = tu2[(size_t)node * 32 + l];
        a0 += bf2f((unsigned short)(tv.x & 0xffff));
        a1 += bf2f((unsigned short)(tv.x >> 16));
        a2 += bf2f((unsigned short)(tv.y & 0xffff));
        a3 += bf2f((unsigned short)(tv.y >> 16));
        int c0 = 4 * l;
        float4 bi = *(const float4*)&bias[c0];
        float4 gm = *(const float4*)&gam[c0];
        float4 bt = *(const float4*)&bet[c0];
        float4 mv = *(const float4*)&mu[c0];
        float4 vr = *(const float4*)&var[c0];
        float sc0 = gm.x * rsqrtf(vr.x + BN_EPS), sh0 = bt.x - mv.x * sc0;
        float sc1 = gm.y * rsqrtf(vr.y + BN_EPS), sh1 = bt.y - mv.y * sc1;
        float sc2 = gm.z * rsqrtf(vr.z + BN_EPS), sh2 = bt.z - mv.z * sc2;
        float sc3 = gm.w * rsqrtf(vr.w + BN_EPS), sh3 = bt.w - mv.w * sc3;
        float o0 = fmaxf((di * a0 + bi.x) * sc0 + sh0, 0.0f);
        float o1 = fmaxf((di * a1 + bi.y) * sc1 + sh1, 0.0f);
        float o2 = fmaxf((di * a2 + bi.z) * sc2 + sh2, 0.0f);
        float o3 = fmaxf((di * a3 + bi.w) * sc3 + sh3, 0.0f);
        uint2 w;
        w.x = pack2bf(o0, o1);
        w.y = pack2bf(o2, o3);
        ((uint2*)out)[(size_t)node * 32 + l] = w;
    }
}

__global__ __launch_bounds__(256)
void gcn_gather64(const unsigned short* __restrict__ t, unsigned short* __restrict__ out,
                  const int* __restrict__ row_ptr, const int* __restrict__ col,
                  const float* __restrict__ dinv,
                  const float* __restrict__ bias,
                  const float* __restrict__ gam, const float* __restrict__ bet,
                  const float* __restrict__ mu,  const float* __restrict__ var,
                  int Nn) {
    int node = (int)((blockIdx.x * 256 + threadIdx.x) >> 6);
    int lane = threadIdx.x & 63;
    if (node >= Nn) return;
    int half = lane >> 5;
    int l    = lane & 31;          // channels 2l, 2l+1 via uint
    int b0 = row_ptr[node], b1 = row_ptr[node + 1];
    float di = dinv[node];
    const unsigned int* tu = (const unsigned int*)t;  // row = 32 uints

    float a0 = 0.f, a1 = 0.f;
    int e = b0;
    for (; e + 32 <= b1; e += 32) {
        int cc[16]; unsigned int f[16];
        #pragma unroll
        for (int u = 0; u < 16; ++u) cc[u] = col[e + 2 * u + half];
        #pragma unroll
        for (int u = 0; u < 16; ++u) f[u] = tu[(size_t)cc[u] * 32 + l];
        #pragma unroll
        for (int u = 0; u < 16; ++u) {
            a0 += bf2f((unsigned short)(f[u] & 0xffff));
            a1 += bf2f((unsigned short)(f[u] >> 16));
        }
    }
    for (; e + 2 <= b1; e += 2) {
        int c = col[e + half];
        unsigned int f = tu[(size_t)c * 32 + l];
        a0 += bf2f((unsigned short)(f & 0xffff));
        a1 += bf2f((unsigned short)(f >> 16));
    }
    if (e < b1 && half == 0) {
        int c = col[e];
        unsigned int f = tu[(size_t)c * 32 + l];
        a0 += bf2f((unsigned short)(f & 0xffff));
        a1 += bf2f((unsigned short)(f >> 16));
    }
    a0 += __shfl_xor(a0, 32);
    a1 += __shfl_xor(a1, 32);

    if (half == 0) {
        unsigned int tv = tu[(size_t)node * 32 + l];
        a0 += bf2f((unsigned short)(tv & 0xffff));
        a1 += bf2f((unsigned short)(tv >> 16));
        int c0 = 2 * l, c1 = 2 * l + 1;
        float sc0 = gam[c0] * rsqrtf(var[c0] + BN_EPS), sh0 = bet[c0] - mu[c0] * sc0;
        float sc1 = gam[c1] * rsqrtf(var[c1] + BN_EPS), sh1 = bet[c1] - mu[c1] * sc1;
        float o0 = fmaxf((di * a0 + bias[c0]) * sc0 + sh0, 0.0f);
        float o1 = fmaxf((di * a1 + bias[c1]) * sc1 + sh1, 0.0f);
        ((unsigned int*)out)[(size_t)node * 32 + l] = pack2bf(o0, o1);
    }
}

// ---------------- parallel pool: wave per 64-node chunk, lane = channel ----------------

__global__ __launch_bounds__(256)
void pool_sum_kernel(const unsigned short* __restrict__ h3, const int* __restrict__ batch,
                     float* __restrict__ sums, int Nn) {
    int wid  = (int)((blockIdx.x * 256 + threadIdx.x) >> 6);
    int lane = threadIdx.x & 63;
    int i0 = wid * 64;
    if (i0 >= Nn) return;
    int i1 = i0 + 64; if (i1 > Nn) i1 = Nn;

    float acc = 0.0f;
    int g = batch[i0];
    for (int i = i0; i < i1; ++i) {
        int gi = batch[i];
        if (gi != g) {
            unsafeAtomicAdd(&sums[g * 64 + lane], acc);
            acc = 0.0f;
            g = gi;
        }
        acc += bf2f(h3[(size_t)i * 64 + lane]);
    }
    unsafeAtomicAdd(&sums[g * 64 + lane], acc);
}

// ---------------- MLP head on pooled sums ----------------

__global__ __launch_bounds__(64)
void mlp_kernel(const float* __restrict__ sums, const int* __restrict__ start,
                const float* __restrict__ Wm1, const float* __restrict__ bm1,
                const float* __restrict__ Wm2, const float* __restrict__ bm2,
                float* __restrict__ out) {
    int g = blockIdx.x;
    int c = threadIdx.x;  // 64
    float cnt = (float)(start[g + 1] - start[g]);
    float pooled = sums[g * 64 + c] / fmaxf(cnt, 1.0f);
    __shared__ float pl[64];
    __shared__ float zl[64];
    pl[c] = pooled;
    __syncthreads();
    float z = bm1[c];
    for (int j = 0; j < 64; ++j) z = fmaf(pl[j], Wm1[j * 64 + c], z);
    z = fmaxf(z, 0.0f);
    zl[c] = z;
    __syncthreads();
    if (c < 10) {
        float o = bm2[c];
        for (int j = 0; j < 64; ++j) o = fmaf(zl[j], Wm2[j * 10 + c], o);
        out[g * 10 + c] = o;
    }
}

// ---------------- launcher ----------------

static inline int cdiv(int a, int b) { return (a + b - 1) / b; }

extern "C" void kernel_launch(void* const* d_in, const int* in_sizes, int n_in,
                              void* d_out, int out_size, void* d_ws, size_t ws_size,
                              hipStream_t stream) {
    const float* x   = (const float*)d_in[0];
    const int* edge  = (const int*)d_in[1];
    const int* batch = (const int*)d_in[2];
    const float* W1  = (const float*)d_in[3];
    const float* b1  = (const float*)d_in[4];
    const float* W2  = (const float*)d_in[5];
    const float* b2  = (const float*)d_in[6];
    const float* W3  = (const float*)d_in[7];
    const float* b3  = (const float*)d_in[8];
    const float* g1  = (const float*)d_in[9];
    const float* be1 = (const float*)d_in[10];
    const float* m1  = (const float*)d_in[11];
    const float* v1  = (const float*)d_in[12];
    const float* g2  = (const float*)d_in[13];
    const float* be2 = (const float*)d_in[14];
    const float* m2  = (const float*)d_in[15];
    const float* v2  = (const float*)d_in[16];
    const float* g3  = (const float*)d_in[17];
    const float* be3 = (const float*)d_in[18];
    const float* m3  = (const float*)d_in[19];
    const float* v3  = (const float*)d_in[20];
    const float* Wm1 = (const float*)d_in[21];
    const float* bm1 = (const float*)d_in[22];
    const float* Wm2 = (const float*)d_in[23];
    const float* bm2 = (const float*)d_in[24];
    float* outp = (float*)d_out;

    const int Nn = in_sizes[0] / 128;
    const int E  = in_sizes[1] / 2;
    const int G  = 128;
    const int* srcv = edge;
    const int* dstv = edge + E;

    // ws layout (bytes):
    // bufA (Nn*128 bf16) | bufB (Nn*128 bf16) | dinv (Nn f32) | col (E int)
    // | bkt (256*BCAP int) | row_ptr (Nn+1) | start (G+1) | sums (G*64 f32)
    // | cursor(256) | bucketBase(256) | w1b/w2b/w3b
    char* wsb = (char*)d_ws;
    unsigned short* bufA = (unsigned short*)wsb;
    unsigned short* bufB = bufA + (size_t)Nn * 128;
    float* dinv    = (float*)(bufB + (size_t)Nn * 128);
    int*   col     = (int*)(dinv + Nn);
    int*   bkt     = col + E;
    int*   row_ptr = bkt + (size_t)256 * BCAP;
    int*   start   = row_ptr + (Nn + 1);
    float* sums    = (float*)(start + (G + 1));
    int*   cursor     = (int*)(sums + G * 64);
    int*   bucketBase = cursor + 256;
    unsigned short* w1b = (unsigned short*)(bucketBase + 256);
    unsigned short* w2b = w1b + 128 * 128;
    unsigned short* w3b = w2b + 128 * 64;

    const int nbkt = cdiv(Nn, 512);

    // ---- CSR build (2 passes) + weight conversion ----
    hipMemsetAsync(cursor, 0, 256 * sizeof(int), stream);
    bucketA_kernel<<<cdiv(E, 4096), 256, 0, stream>>>(srcv, dstv, cursor, bkt, E);
    scanB_kernel<<<1, 256, 0, stream>>>(cursor, bucketBase, row_ptr, E, Nn);
    orderB_kernel<<<nbkt, 256, 0, stream>>>(bkt, cursor, bucketBase, row_ptr, dinv, col,
                                            batch, start, Nn, G);
    convw_kernel<<<64, 256, 0, stream>>>(W1, W2, W3, w1b, w2b, w3b);

    // ---- layer 1: t' = dinv*(x @ W1); gather -> bufB ----
    gemm_mfma<128, 128, true><<<cdiv(Nn, 64), 256, 0, stream>>>(x, w1b, dinv, bufA, Nn);
    gcn_gather128<<<cdiv(Nn, 4), 256, 0, stream>>>(bufA, bufB, row_ptr, col, dinv,
                                                   b1, g1, be1, m1, v1, Nn);

    // ---- layer 2 ----
    gemm_mfma<128, 64, false><<<cdiv(Nn, 64), 256, 0, stream>>>(bufB, w2b, dinv, bufA, Nn);
    gcn_gather64<<<cdiv(Nn, 4), 256, 0, stream>>>(bufA, bufB, row_ptr, col, dinv,
                                                  b2, g2, be2, m2, v2, Nn);

    // ---- layer 3 ----
    gemm_mfma<64, 64, false><<<cdiv(Nn, 64), 256, 0, stream>>>(bufB, w3b, dinv, bufA, Nn);
    gcn_gather64<<<cdiv(Nn, 4), 256, 0, stream>>>(bufA, bufB, row_ptr, col, dinv,
                                                  b3, g3, be3, m3, v3, Nn);

    // ---- pool + MLP ----
    hipMemsetAsync(sums, 0, (size_t)G * 64 * sizeof(float), stream);
    pool_sum_kernel<<<cdiv(Nn, 256), 256, 0, stream>>>(bufB, batch, sums, Nn);
    mlp_kernel<<<G, 64, 0, stream>>>(sums, start, Wm1, bm1, Wm2, bm2, outp);
}

// Round 16
// 323.145 us; speedup vs baseline: 1.2958x; 1.2958x over previous
//
#include <hip/hip_runtime.h>
#include <math.h>

#define BN_EPS 1e-5f
#define BCAP 12544   // per-bucket edge capacity (expected ~6250 for uniform dsts)

using bf16x8 = __attribute__((ext_vector_type(8))) short;
using f32x4  = __attribute__((ext_vector_type(4))) float;

// ---------------- bf16 helpers (RNE) ----------------

__device__ __forceinline__ float bf2f(unsigned short u) {
    union { unsigned int i; float f; } v; v.i = ((unsigned int)u) << 16; return v.f;
}
__device__ __forceinline__ unsigned short f2bf(float f) {
    union { float f; unsigned int i; } v; v.f = f;
    unsigned int lsb = (v.i >> 16) & 1u;
    v.i += 0x7fffu + lsb;
    return (unsigned short)(v.i >> 16);
}
__device__ __forceinline__ unsigned int pack2bf(float a, float b) {
    return (unsigned int)f2bf(a) | ((unsigned int)f2bf(b) << 16);
}

// ---------------- CSR build (2-kernel hierarchical) ----------------

__global__ __launch_bounds__(256)
void bucketA_kernel(const int* __restrict__ srcv, const int* __restrict__ dstv,
                    int* __restrict__ cursor, int* __restrict__ bkt, int E) {
    __shared__ int hist[256], base[256], lcur[256];
    __shared__ int2 stage[4096];
    int tid = threadIdx.x;
    hist[tid] = 0; lcur[tid] = 0;
    __syncthreads();
    int e0 = blockIdx.x * 4096;
    int nmax = E - e0; if (nmax > 4096) nmax = 4096;

    #pragma unroll
    for (int u = 0; u < 16; ++u) {
        int idx = u * 256 + tid;
        if (idx < nmax) {
            int e = e0 + idx;
            int d = dstv[e], s = srcv[e];
            stage[idx] = make_int2(d, s);
            atomicAdd(&hist[d >> 9], 1);
        }
    }
    __syncthreads();
    if (hist[tid] > 0) base[tid] = atomicAdd(&cursor[tid], hist[tid]);
    __syncthreads();
    #pragma unroll
    for (int u = 0; u < 16; ++u) {
        int idx = u * 256 + tid;
        if (idx < nmax) {
            int2 ds = stage[idx];
            int b = ds.x >> 9;
            int dl = ds.x & 511;
            int slot = base[b] + atomicAdd(&lcur[b], 1);
            if (slot < BCAP)
                bkt[b * BCAP + slot] = ds.y | (dl << 17);
        }
    }
}

__global__ void scanB_kernel(const int* __restrict__ cursor, int* __restrict__ bucketBase,
                             int* __restrict__ row_ptr, int E, int Nn) {
    __shared__ int s[256];
    int t = threadIdx.x;
    int v = cursor[t];
    s[t] = v;
    __syncthreads();
    for (int off = 1; off < 256; off <<= 1) {
        int add = (t >= off) ? s[t - off] : 0;
        __syncthreads();
        s[t] += add;
        __syncthreads();
    }
    bucketBase[t] = s[t] - v;
    if (t == 0) row_ptr[Nn] = E;
}

__global__ __launch_bounds__(256)
void orderB_kernel(const int* __restrict__ bkt, const int* __restrict__ cursor,
                   const int* __restrict__ bucketBase,
                   int* __restrict__ row_ptr, float* __restrict__ dinv, int* __restrict__ col,
                   const int* __restrict__ batch, int* __restrict__ start,
                   int Nn, int G) {
    __shared__ int hist[512];
    __shared__ int scan_s[256];
    int b = blockIdx.x;
    int lo = b << 9;
    if (lo >= Nn) return;
    int hi = lo + 512; if (hi > Nn) hi = Nn;
    int cnt = cursor[b];
    int g0 = b * BCAP;
    int c0 = bucketBase[b];
    int tid = threadIdx.x;
    hist[tid] = 0; hist[tid + 256] = 0;
    __syncthreads();
    for (int i = tid; i < cnt; i += 256)
        atomicAdd(&hist[(((unsigned int)bkt[g0 + i]) >> 17) & 511], 1);
    __syncthreads();
    int a0 = hist[2 * tid], a1 = hist[2 * tid + 1];
    int n0 = lo + 2 * tid, n1 = n0 + 1;
    if (n0 < Nn) dinv[n0] = rsqrtf((float)a0 + 1.0f);
    if (n1 < Nn) dinv[n1] = rsqrtf((float)a1 + 1.0f);
    int pairsum = a0 + a1;
    scan_s[tid] = pairsum;
    __syncthreads();
    for (int off = 1; off < 256; off <<= 1) {
        int add = (tid >= off) ? scan_s[tid - off] : 0;
        __syncthreads();
        scan_s[tid] += add;
        __syncthreads();
    }
    int excl = scan_s[tid] - pairsum;
    __syncthreads();
    if (n0 < Nn) row_ptr[n0] = c0 + excl;
    if (n1 < Nn) row_ptr[n1] = c0 + excl + a0;
    hist[2 * tid] = excl;
    hist[2 * tid + 1] = excl + a0;
    __syncthreads();
    for (int i = tid; i < cnt; i += 256) {
        int en = bkt[g0 + i];
        int dl = (((unsigned int)en) >> 17) & 511;
        int slot = atomicAdd(&hist[dl], 1);
        col[c0 + slot] = en & 0x1ffff;
    }
    for (int i = lo + tid; i < hi; i += 256) {
        int bb = batch[i];
        if (i == 0) {
            for (int g = 0; g <= bb; ++g) start[g] = 0;
        } else {
            int p = batch[i - 1];
            for (int g = p + 1; g <= bb; ++g) start[g] = i;
        }
        if (i == Nn - 1) {
            for (int g = bb + 1; g <= G; ++g) start[g] = Nn;
        }
    }
}

// ---------------- weight f32 -> bf16 conversion ----------------

__global__ void convw_kernel(const float* __restrict__ W1, const float* __restrict__ W2,
                             const float* __restrict__ W3,
                             unsigned short* __restrict__ w1b, unsigned short* __restrict__ w2b,
                             unsigned short* __restrict__ w3b) {
    int i = blockIdx.x * 256 + threadIdx.x;
    if (i < 128 * 128) w1b[i] = f2bf(W1[i]);
    if (i < 128 * 64)  w2b[i] = f2bf(W2[i]);
    if (i < 64 * 64)   w3b[i] = f2bf(W3[i]);
}

// ---------------- MFMA GEMM: C[M,N](bf16) = dinv[row] * (A[M,K] @ Wb[K,N]) ----------------

template<int K, int N, bool AF32>
__global__ __launch_bounds__(256)
void gemm_mfma(const void* __restrict__ Ap, const unsigned short* __restrict__ Wb,
               const float* __restrict__ dinv, unsigned short* __restrict__ C, int M) {
    constexpr int KF = K / 32;
    constexpr int NF = N / 16;
    __shared__ __align__(16) unsigned short ldsW[KF * NF * 64 * 8];

    for (int c = threadIdx.x; c < K * N / 8; c += 256) {
        int e0 = c * 8;
        int k = e0 / N, n0 = e0 % N;
        uint4 v = *(const uint4*)&Wb[e0];
        unsigned short w[8];
        w[0] = (unsigned short)(v.x & 0xffff); w[1] = (unsigned short)(v.x >> 16);
        w[2] = (unsigned short)(v.y & 0xffff); w[3] = (unsigned short)(v.y >> 16);
        w[4] = (unsigned short)(v.z & 0xffff); w[5] = (unsigned short)(v.z >> 16);
        w[6] = (unsigned short)(v.w & 0xffff); w[7] = (unsigned short)(v.w >> 16);
        int j    = k & 7;
        int lhi  = ((k & 31) >> 3) << 4;
        int fbase = (k >> 5) * NF;
        #pragma unroll
        for (int u = 0; u < 8; ++u) {
            int n = n0 + u;
            int f = fbase + (n >> 4);
            int l = lhi | (n & 15);
            ldsW[(f * 64 + l) * 8 + j] = w[u];
        }
    }
    __syncthreads();

    const int wave = threadIdx.x >> 6;
    const int lane = threadIdx.x & 63;
    const int r0   = blockIdx.x * 64 + wave * 16;

    int arow = r0 + (lane & 15);
    if (arow >= M) arow = M - 1;
    const int kc0 = (lane >> 4) * 8;
    bf16x8 af[KF];
    #pragma unroll
    for (int k = 0; k < KF; ++k) {
        if constexpr (AF32) {
            const float* A = (const float*)Ap;
            const float4* p = (const float4*)&A[(size_t)arow * K + k * 32 + kc0];
            float4 u0 = p[0], u1 = p[1];
            unsigned int q0 = pack2bf(u0.x, u0.y), q1 = pack2bf(u0.z, u0.w);
            unsigned int q2 = pack2bf(u1.x, u1.y), q3 = pack2bf(u1.z, u1.w);
            bf16x8 a;
            a[0] = (short)(q0 & 0xffff); a[1] = (short)(q0 >> 16);
            a[2] = (short)(q1 & 0xffff); a[3] = (short)(q1 >> 16);
            a[4] = (short)(q2 & 0xffff); a[5] = (short)(q2 >> 16);
            a[6] = (short)(q3 & 0xffff); a[7] = (short)(q3 >> 16);
            af[k] = a;
        } else {
            const unsigned short* A = (const unsigned short*)Ap;
            af[k] = *(const bf16x8*)&A[(size_t)arow * K + k * 32 + kc0];
        }
    }

    const int colb = lane & 15;
    const int rsub = (lane >> 4) * 4;
    float dv[4];
    #pragma unroll
    for (int j = 0; j < 4; ++j) {
        int row = r0 + rsub + j;
        dv[j] = (row < M) ? dinv[row] : 0.0f;
    }
    #pragma unroll
    for (int n = 0; n < NF; ++n) {
        f32x4 acc = {0.f, 0.f, 0.f, 0.f};
        #pragma unroll
        for (int k = 0; k < KF; ++k) {
            bf16x8 bf = *(const bf16x8*)&ldsW[((k * NF + n) * 64 + lane) * 8];
            acc = __builtin_amdgcn_mfma_f32_16x16x32_bf16(af[k], bf, acc, 0, 0, 0);
        }
        int col = n * 16 + colb;
        #pragma unroll
        for (int j = 0; j < 4; ++j) {
            int row = r0 + rsub + j;
            if (row < M) C[(size_t)row * N + col] = f2bf(acc[j] * dv[j]);
        }
    }
}

// ---------------- fused gather + bias + BN + ReLU (dual-edge half-wave) ----------------
// batch ladder 8/4/2/1 pairs matched to deg~16 distribution.

__global__ __launch_bounds__(256)
void gcn_gather128(const unsigned short* __restrict__ t, unsigned short* __restrict__ out,
                   const int* __restrict__ row_ptr, const int* __restrict__ col,
                   const float* __restrict__ dinv,
                   const float* __restrict__ bias,
                   const float* __restrict__ gam, const float* __restrict__ bet,
                   const float* __restrict__ mu,  const float* __restrict__ var,
                   int Nn) {
    int node = (int)((blockIdx.x * 256 + threadIdx.x) >> 6);
    int lane = threadIdx.x & 63;
    if (node >= Nn) return;
    int half = lane >> 5;
    int l    = lane & 31;          // channels 4l..4l+3 via uint2
    int b0 = row_ptr[node], b1 = row_ptr[node + 1];
    float di = dinv[node];
    const uint2* tu2 = (const uint2*)t;

    float a0 = 0.f, a1 = 0.f, a2 = 0.f, a3 = 0.f;
    int e = b0;
    #define G128_BATCH(P)                                                    \
    for (; e + 2*(P) <= b1; e += 2*(P)) {                                    \
        int cc[P]; uint2 f[P];                                               \
        _Pragma("unroll")                                                    \
        for (int u = 0; u < (P); ++u) cc[u] = col[e + 2*u + half];           \
        _Pragma("unroll")                                                    \
        for (int u = 0; u < (P); ++u) f[u] = tu2[(size_t)cc[u] * 32 + l];    \
        _Pragma("unroll")                                                    \
        for (int u = 0; u < (P); ++u) {                                      \
            a0 += bf2f((unsigned short)(f[u].x & 0xffff));                   \
            a1 += bf2f((unsigned short)(f[u].x >> 16));                      \
            a2 += bf2f((unsigned short)(f[u].y & 0xffff));                   \
            a3 += bf2f((unsigned short)(f[u].y >> 16));                      \
        }                                                                    \
    }
    G128_BATCH(8)
    G128_BATCH(4)
    G128_BATCH(2)
    G128_BATCH(1)
    #undef G128_BATCH
    if (e < b1 && half == 0) {
        int c = col[e];
        uint2 f = tu2[(size_t)c * 32 + l];
        a0 += bf2f((unsigned short)(f.x & 0xffff));
        a1 += bf2f((unsigned short)(f.x >> 16));
        a2 += bf2f((unsigned short)(f.y & 0xffff));
        a3 += bf2f((unsigned short)(f.y >> 16));
    }
    a0 += __shfl_xor(a0, 32);
    a1 += __shfl_xor(a1, 32);
    a2 += __shfl_xor(a2, 32);
    a3 += __shfl_xor(a3, 32);

    if (half == 0) {
        uint2 tv = tu2[(size_t)node * 32 + l];
        a0 += bf2f((unsigned short)(tv.x & 0xffff));
        a1 += bf2f((unsigned short)(tv.x >> 16));
        a2 += bf2f((unsigned short)(tv.y & 0xffff));
        a3 += bf2f((unsigned short)(tv.y >> 16));
        int c0 = 4 * l;
        float4 bi = *(const float4*)&bias[c0];
        float4 gm = *(const float4*)&gam[c0];
        float4 bt = *(const float4*)&bet[c0];
        float4 mv = *(const float4*)&mu[c0];
        float4 vr = *(const float4*)&var[c0];
        float sc0 = gm.x * rsqrtf(vr.x + BN_EPS), sh0 = bt.x - mv.x * sc0;
        float sc1 = gm.y * rsqrtf(vr.y + BN_EPS), sh1 = bt.y - mv.y * sc1;
        float sc2 = gm.z * rsqrtf(vr.z + BN_EPS), sh2 = bt.z - mv.z * sc2;
        float sc3 = gm.w * rsqrtf(vr.w + BN_EPS), sh3 = bt.w - mv.w * sc3;
        float o0 = fmaxf((di * a0 + bi.x) * sc0 + sh0, 0.0f);
        float o1 = fmaxf((di * a1 + bi.y) * sc1 + sh1, 0.0f);
        float o2 = fmaxf((di * a2 + bi.z) * sc2 + sh2, 0.0f);
        float o3 = fmaxf((di * a3 + bi.w) * sc3 + sh3, 0.0f);
        uint2 w;
        w.x = pack2bf(o0, o1);
        w.y = pack2bf(o2, o3);
        ((uint2*)out)[(size_t)node * 32 + l] = w;
    }
}

__global__ __launch_bounds__(256)
void gcn_gather64(const unsigned short* __restrict__ t, unsigned short* __restrict__ out,
                  const int* __restrict__ row_ptr, const int* __restrict__ col,
                  const float* __restrict__ dinv,
                  const float* __restrict__ bias,
                  const float* __restrict__ gam, const float* __restrict__ bet,
                  const float* __restrict__ mu,  const float* __restrict__ var,
                  int Nn) {
    int node = (int)((blockIdx.x * 256 + threadIdx.x) >> 6);
    int lane = threadIdx.x & 63;
    if (node >= Nn) return;
    int half = lane >> 5;
    int l    = lane & 31;          // channels 2l, 2l+1 via uint
    int b0 = row_ptr[node], b1 = row_ptr[node + 1];
    float di = dinv[node];
    const unsigned int* tu = (const unsigned int*)t;

    float a0 = 0.f, a1 = 0.f;
    int e = b0;
    #define G64_BATCH(P)                                                     \
    for (; e + 2*(P) <= b1; e += 2*(P)) {                                    \
        int cc[P]; unsigned int f[P];                                        \
        _Pragma("unroll")                                                    \
        for (int u = 0; u < (P); ++u) cc[u] = col[e + 2*u + half];           \
        _Pragma("unroll")                                                    \
        for (int u = 0; u < (P); ++u) f[u] = tu[(size_t)cc[u] * 32 + l];     \
        _Pragma("unroll")                                                    \
        for (int u = 0; u < (P); ++u) {                                      \
            a0 += bf2f((unsigned short)(f[u] & 0xffff));                     \
            a1 += bf2f((unsigned short)(f[u] >> 16));                        \
        }                                                                    \
    }
    G64_BATCH(8)
    G64_BATCH(4)
    G64_BATCH(2)
    G64_BATCH(1)
    #undef G64_BATCH
    if (e < b1 && half == 0) {
        int c = col[e];
        unsigned int f = tu[(size_t)c * 32 + l];
        a0 += bf2f((unsigned short)(f & 0xffff));
        a1 += bf2f((unsigned short)(f >> 16));
    }
    a0 += __shfl_xor(a0, 32);
    a1 += __shfl_xor(a1, 32);

    if (half == 0) {
        unsigned int tv = tu[(size_t)node * 32 + l];
        a0 += bf2f((unsigned short)(tv & 0xffff));
        a1 += bf2f((unsigned short)(tv >> 16));
        int c0 = 2 * l, c1 = 2 * l + 1;
        float sc0 = gam[c0] * rsqrtf(var[c0] + BN_EPS), sh0 = bet[c0] - mu[c0] * sc0;
        float sc1 = gam[c1] * rsqrtf(var[c1] + BN_EPS), sh1 = bet[c1] - mu[c1] * sc1;
        float o0 = fmaxf((di * a0 + bias[c0]) * sc0 + sh0, 0.0f);
        float o1 = fmaxf((di * a1 + bias[c1]) * sc1 + sh1, 0.0f);
        ((unsigned int*)out)[(size_t)node * 32 + l] = pack2bf(o0, o1);
    }
}

// ---------------- parallel pool: wave per 64-node chunk, lane = channel ----------------

__global__ __launch_bounds__(256)
void pool_sum_kernel(const unsigned short* __restrict__ h3, const int* __restrict__ batch,
                     float* __restrict__ sums, int Nn) {
    int wid  = (int)((blockIdx.x * 256 + threadIdx.x) >> 6);
    int lane = threadIdx.x & 63;
    int i0 = wid * 64;
    if (i0 >= Nn) return;
    int i1 = i0 + 64; if (i1 > Nn) i1 = Nn;

    float acc = 0.0f;
    int g = batch[i0];
    for (int i = i0; i < i1; ++i) {
        int gi = batch[i];
        if (gi != g) {
            unsafeAtomicAdd(&sums[g * 64 + lane], acc);
            acc = 0.0f;
            g = gi;
        }
        acc += bf2f(h3[(size_t)i * 64 + lane]);
    }
    unsafeAtomicAdd(&sums[g * 64 + lane], acc);
}

// ---------------- MLP head on pooled sums ----------------

__global__ __launch_bounds__(64)
void mlp_kernel(const float* __restrict__ sums, const int* __restrict__ start,
                const float* __restrict__ Wm1, const float* __restrict__ bm1,
                const float* __restrict__ Wm2, const float* __restrict__ bm2,
                float* __restrict__ out) {
    int g = blockIdx.x;
    int c = threadIdx.x;  // 64
    float cnt = (float)(start[g + 1] - start[g]);
    float pooled = sums[g * 64 + c] / fmaxf(cnt, 1.0f);
    __shared__ float pl[64];
    __shared__ float zl[64];
    pl[c] = pooled;
    __syncthreads();
    float z = bm1[c];
    for (int j = 0; j < 64; ++j) z = fmaf(pl[j], Wm1[j * 64 + c], z);
    z = fmaxf(z, 0.0f);
    zl[c] = z;
    __syncthreads();
    if (c < 10) {
        float o = bm2[c];
        for (int j = 0; j < 64; ++j) o = fmaf(zl[j], Wm2[j * 10 + c], o);
        out[g * 10 + c] = o;
    }
}

// ---------------- launcher ----------------

static inline int cdiv(int a, int b) { return (a + b - 1) / b; }

extern "C" void kernel_launch(void* const* d_in, const int* in_sizes, int n_in,
                              void* d_out, int out_size, void* d_ws, size_t ws_size,
                              hipStream_t stream) {
    const float* x   = (const float*)d_in[0];
    const int* edge  = (const int*)d_in[1];
    const int* batch = (const int*)d_in[2];
    const float* W1  = (const float*)d_in[3];
    const float* b1  = (const float*)d_in[4];
    const float* W2  = (const float*)d_in[5];
    const float* b2  = (const float*)d_in[6];
    const float* W3  = (const float*)d_in[7];
    const float* b3  = (const float*)d_in[8];
    const float* g1  = (const float*)d_in[9];
    const float* be1 = (const float*)d_in[10];
    const float* m1  = (const float*)d_in[11];
    const float* v1  = (const float*)d_in[12];
    const float* g2  = (const float*)d_in[13];
    const float* be2 = (const float*)d_in[14];
    const float* m2  = (const float*)d_in[15];
    const float* v2  = (const float*)d_in[16];
    const float* g3  = (const float*)d_in[17];
    const float* be3 = (const float*)d_in[18];
    const float* m3  = (const float*)d_in[19];
    const float* v3  = (const float*)d_in[20];
    const float* Wm1 = (const float*)d_in[21];
    const float* bm1 = (const float*)d_in[22];
    const float* Wm2 = (const float*)d_in[23];
    const float* bm2 = (const float*)d_in[24];
    float* outp = (float*)d_out;

    const int Nn = in_sizes[0] / 128;
    const int E  = in_sizes[1] / 2;
    const int G  = 128;
    const int* srcv = edge;
    const int* dstv = edge + E;

    char* wsb = (char*)d_ws;
    unsigned short* bufA = (unsigned short*)wsb;
    unsigned short* bufB = bufA + (size_t)Nn * 128;
    float* dinv    = (float*)(bufB + (size_t)Nn * 128);
    int*   col     = (int*)(dinv + Nn);
    int*   bkt     = col + E;
    int*   row_ptr = bkt + (size_t)256 * BCAP;
    int*   start   = row_ptr + (Nn + 1);
    float* sums    = (float*)(start + (G + 1));
    int*   cursor     = (int*)(sums + G * 64);
    int*   bucketBase = cursor + 256;
    unsigned short* w1b = (unsigned short*)(bucketBase + 256);
    unsigned short* w2b = w1b + 128 * 128;
    unsigned short* w3b = w2b + 128 * 64;

    const int nbkt = cdiv(Nn, 512);

    // ---- CSR build + weight conversion ----
    hipMemsetAsync(cursor, 0, 256 * sizeof(int), stream);
    bucketA_kernel<<<cdiv(E, 4096), 256, 0, stream>>>(srcv, dstv, cursor, bkt, E);
    scanB_kernel<<<1, 256, 0, stream>>>(cursor, bucketBase, row_ptr, E, Nn);
    orderB_kernel<<<nbkt, 256, 0, stream>>>(bkt, cursor, bucketBase, row_ptr, dinv, col,
                                            batch, start, Nn, G);
    convw_kernel<<<64, 256, 0, stream>>>(W1, W2, W3, w1b, w2b, w3b);

    // ---- layer 1: t' = dinv*(x @ W1); gather -> bufB ----
    gemm_mfma<128, 128, true><<<cdiv(Nn, 64), 256, 0, stream>>>(x, w1b, dinv, bufA, Nn);
    gcn_gather128<<<cdiv(Nn, 4), 256, 0, stream>>>(bufA, bufB, row_ptr, col, dinv,
                                                   b1, g1, be1, m1, v1, Nn);

    // ---- layer 2 ----
    gemm_mfma<128, 64, false><<<cdiv(Nn, 64), 256, 0, stream>>>(bufB, w2b, dinv, bufA, Nn);
    gcn_gather64<<<cdiv(Nn, 4), 256, 0, stream>>>(bufA, bufB, row_ptr, col, dinv,
                                                  b2, g2, be2, m2, v2, Nn);

    // ---- layer 3 ----
    gemm_mfma<64, 64, false><<<cdiv(Nn, 64), 256, 0, stream>>>(bufB, w3b, dinv, bufA, Nn);
    gcn_gather64<<<cdiv(Nn, 4), 256, 0, stream>>>(bufA, bufB, row_ptr, col, dinv,
                                                  b3, g3, be3, m3, v3, Nn);

    // ---- pool + MLP ----
    hipMemsetAsync(sums, 0, (size_t)G * 64 * sizeof(float), stream);
    pool_sum_kernel<<<cdiv(Nn, 256), 256, 0, stream>>>(bufB, batch, sums, Nn);
    mlp_kernel<<<G, 64, 0, stream>>>(sums, start, Wm1, bm1, Wm2, bm2, outp);
}

// Round 17
// 320.442 us; speedup vs baseline: 1.3067x; 1.0084x over previous
//
#include <hip/hip_runtime.h>
#include <math.h>

#define BN_EPS 1e-5f
#define BCAP 12544   // per-bucket edge capacity (expected ~6250 for uniform dsts)

using bf16x8 = __attribute__((ext_vector_type(8))) short;
using f32x4  = __attribute__((ext_vector_type(4))) float;

// ---------------- bf16 helpers (RNE) ----------------

__device__ __forceinline__ float bf2f(unsigned short u) {
    union { unsigned int i; float f; } v; v.i = ((unsigned int)u) << 16; return v.f;
}
__device__ __forceinline__ unsigned short f2bf(float f) {
    union { float f; unsigned int i; } v; v.f = f;
    unsigned int lsb = (v.i >> 16) & 1u;
    v.i += 0x7fffu + lsb;
    return (unsigned short)(v.i >> 16);
}
__device__ __forceinline__ unsigned int pack2bf(float a, float b) {
    return (unsigned int)f2bf(a) | ((unsigned int)f2bf(b) << 16);
}

// ---------------- CSR build (2-kernel hierarchical) ----------------

// Phase A: no LDS staging (re-read via L2) -> 3KB LDS, high occupancy.
__global__ __launch_bounds__(256)
void bucketA_kernel(const int* __restrict__ srcv, const int* __restrict__ dstv,
                    int* __restrict__ cursor, int* __restrict__ bkt, int E) {
    __shared__ int hist[256], base[256], lcur[256];
    int tid = threadIdx.x;
    hist[tid] = 0; lcur[tid] = 0;
    __syncthreads();
    int e0 = blockIdx.x * 4096;
    int nmax = E - e0; if (nmax > 4096) nmax = 4096;

    #pragma unroll
    for (int u = 0; u < 16; ++u) {
        int idx = u * 256 + tid;
        if (idx < nmax) atomicAdd(&hist[dstv[e0 + idx] >> 9], 1);
    }
    __syncthreads();
    if (hist[tid] > 0) base[tid] = atomicAdd(&cursor[tid], hist[tid]);
    __syncthreads();
    #pragma unroll
    for (int u = 0; u < 16; ++u) {
        int idx = u * 256 + tid;
        if (idx < nmax) {
            int e = e0 + idx;
            int d = dstv[e], s = srcv[e];   // L2-hot second read
            int b = d >> 9;
            int dl = d & 511;
            int slot = base[b] + atomicAdd(&lcur[b], 1);
            if (slot < BCAP)
                bkt[b * BCAP + slot] = s | (dl << 17);
        }
    }
}

// 1 block: scan cursor -> bucketBase; row_ptr[Nn]=E; zero the pool sums.
__global__ void scanB_kernel(const int* __restrict__ cursor, int* __restrict__ bucketBase,
                             int* __restrict__ row_ptr, float* __restrict__ sums,
                             int E, int Nn, int G) {
    __shared__ int s[256];
    int t = threadIdx.x;
    int v = cursor[t];
    s[t] = v;
    __syncthreads();
    for (int off = 1; off < 256; off <<= 1) {
        int add = (t >= off) ? s[t - off] : 0;
        __syncthreads();
        s[t] += add;
        __syncthreads();
    }
    bucketBase[t] = s[t] - v;
    if (t == 0) row_ptr[Nn] = E;
    for (int i = t; i < G * 64; i += 256) sums[i] = 0.0f;
}

__global__ __launch_bounds__(256)
void orderB_kernel(const int* __restrict__ bkt, const int* __restrict__ cursor,
                   const int* __restrict__ bucketBase,
                   int* __restrict__ row_ptr, float* __restrict__ dinv, int* __restrict__ col,
                   const int* __restrict__ batch, int* __restrict__ start,
                   int Nn, int G) {
    __shared__ int hist[512];
    __shared__ int scan_s[256];
    int b = blockIdx.x;
    int lo = b << 9;
    if (lo >= Nn) return;
    int hi = lo + 512; if (hi > Nn) hi = Nn;
    int cnt = cursor[b];
    int g0 = b * BCAP;
    int c0 = bucketBase[b];
    int tid = threadIdx.x;
    hist[tid] = 0; hist[tid + 256] = 0;
    __syncthreads();
    for (int i = tid; i < cnt; i += 256)
        atomicAdd(&hist[(((unsigned int)bkt[g0 + i]) >> 17) & 511], 1);
    __syncthreads();
    int a0 = hist[2 * tid], a1 = hist[2 * tid + 1];
    int n0 = lo + 2 * tid, n1 = n0 + 1;
    if (n0 < Nn) dinv[n0] = rsqrtf((float)a0 + 1.0f);
    if (n1 < Nn) dinv[n1] = rsqrtf((float)a1 + 1.0f);
    int pairsum = a0 + a1;
    scan_s[tid] = pairsum;
    __syncthreads();
    for (int off = 1; off < 256; off <<= 1) {
        int add = (tid >= off) ? scan_s[tid - off] : 0;
        __syncthreads();
        scan_s[tid] += add;
        __syncthreads();
    }
    int excl = scan_s[tid] - pairsum;
    __syncthreads();
    if (n0 < Nn) row_ptr[n0] = c0 + excl;
    if (n1 < Nn) row_ptr[n1] = c0 + excl + a0;
    hist[2 * tid] = excl;
    hist[2 * tid + 1] = excl + a0;
    __syncthreads();
    for (int i = tid; i < cnt; i += 256) {
        int en = bkt[g0 + i];
        int dl = (((unsigned int)en) >> 17) & 511;
        int slot = atomicAdd(&hist[dl], 1);
        col[c0 + slot] = en & 0x1ffff;
    }
    for (int i = lo + tid; i < hi; i += 256) {
        int bb = batch[i];
        if (i == 0) {
            for (int g = 0; g <= bb; ++g) start[g] = 0;
        } else {
            int p = batch[i - 1];
            for (int g = p + 1; g <= bb; ++g) start[g] = i;
        }
        if (i == Nn - 1) {
            for (int g = bb + 1; g <= G; ++g) start[g] = Nn;
        }
    }
}

// ---------------- MFMA GEMM: C[M,N](bf16) = dinv[row] * (A[M,K] @ W[K,N]) ----------------
// W is f32 in global; converted to bf16 during the LDS B-fragment fill (same RNE as before).

template<int K, int N, bool AF32>
__global__ __launch_bounds__(256)
void gemm_mfma(const void* __restrict__ Ap, const float* __restrict__ Wf,
               const float* __restrict__ dinv, unsigned short* __restrict__ C, int M) {
    constexpr int KF = K / 32;
    constexpr int NF = N / 16;
    __shared__ __align__(16) unsigned short ldsW[KF * NF * 64 * 8];

    for (int c = threadIdx.x; c < K * N / 8; c += 256) {
        int e0 = c * 8;
        int k = e0 / N, n0 = e0 % N;
        const float4* wp = (const float4*)&Wf[e0];
        float4 v0 = wp[0], v1 = wp[1];
        unsigned short w[8];
        w[0] = f2bf(v0.x); w[1] = f2bf(v0.y); w[2] = f2bf(v0.z); w[3] = f2bf(v0.w);
        w[4] = f2bf(v1.x); w[5] = f2bf(v1.y); w[6] = f2bf(v1.z); w[7] = f2bf(v1.w);
        int j    = k & 7;
        int lhi  = ((k & 31) >> 3) << 4;
        int fbase = (k >> 5) * NF;
        #pragma unroll
        for (int u = 0; u < 8; ++u) {
            int n = n0 + u;
            int f = fbase + (n >> 4);
            int l = lhi | (n & 15);
            ldsW[(f * 64 + l) * 8 + j] = w[u];
        }
    }
    __syncthreads();

    const int wave = threadIdx.x >> 6;
    const int lane = threadIdx.x & 63;
    const int r0   = blockIdx.x * 64 + wave * 16;

    int arow = r0 + (lane & 15);
    if (arow >= M) arow = M - 1;
    const int kc0 = (lane >> 4) * 8;
    bf16x8 af[KF];
    #pragma unroll
    for (int k = 0; k < KF; ++k) {
        if constexpr (AF32) {
            const float* A = (const float*)Ap;
            const float4* p = (const float4*)&A[(size_t)arow * K + k * 32 + kc0];
            float4 u0 = p[0], u1 = p[1];
            unsigned int q0 = pack2bf(u0.x, u0.y), q1 = pack2bf(u0.z, u0.w);
            unsigned int q2 = pack2bf(u1.x, u1.y), q3 = pack2bf(u1.z, u1.w);
            bf16x8 a;
            a[0] = (short)(q0 & 0xffff); a[1] = (short)(q0 >> 16);
            a[2] = (short)(q1 & 0xffff); a[3] = (short)(q1 >> 16);
            a[4] = (short)(q2 & 0xffff); a[5] = (short)(q2 >> 16);
            a[6] = (short)(q3 & 0xffff); a[7] = (short)(q3 >> 16);
            af[k] = a;
        } else {
            const unsigned short* A = (const unsigned short*)Ap;
            af[k] = *(const bf16x8*)&A[(size_t)arow * K + k * 32 + kc0];
        }
    }

    const int colb = lane & 15;
    const int rsub = (lane >> 4) * 4;
    float dv[4];
    #pragma unroll
    for (int j = 0; j < 4; ++j) {
        int row = r0 + rsub + j;
        dv[j] = (row < M) ? dinv[row] : 0.0f;
    }
    #pragma unroll
    for (int n = 0; n < NF; ++n) {
        f32x4 acc = {0.f, 0.f, 0.f, 0.f};
        #pragma unroll
        for (int k = 0; k < KF; ++k) {
            bf16x8 bf = *(const bf16x8*)&ldsW[((k * NF + n) * 64 + lane) * 8];
            acc = __builtin_amdgcn_mfma_f32_16x16x32_bf16(af[k], bf, acc, 0, 0, 0);
        }
        int col = n * 16 + colb;
        #pragma unroll
        for (int j = 0; j < 4; ++j) {
            int row = r0 + rsub + j;
            if (row < M) C[(size_t)row * N + col] = f2bf(acc[j] * dv[j]);
        }
    }
}

// ---------------- fused gather + bias + BN + ReLU (dual-edge half-wave) ----------------

__global__ __launch_bounds__(256)
void gcn_gather128(const unsigned short* __restrict__ t, unsigned short* __restrict__ out,
                   const int* __restrict__ row_ptr, const int* __restrict__ col,
                   const float* __restrict__ dinv,
                   const float* __restrict__ bias,
                   const float* __restrict__ gam, const float* __restrict__ bet,
                   const float* __restrict__ mu,  const float* __restrict__ var,
                   int Nn) {
    int node = (int)((blockIdx.x * 256 + threadIdx.x) >> 6);
    int lane = threadIdx.x & 63;
    if (node >= Nn) return;
    int half = lane >> 5;
    int l    = lane & 31;
    int b0 = row_ptr[node], b1 = row_ptr[node + 1];
    float di = dinv[node];
    const uint2* tu2 = (const uint2*)t;

    float a0 = 0.f, a1 = 0.f, a2 = 0.f, a3 = 0.f;
    int e = b0;
    #define G128_BATCH(P)                                                    \
    for (; e + 2*(P) <= b1; e += 2*(P)) {                                    \
        int cc[P]; uint2 f[P];                                               \
        _Pragma("unroll")                                                    \
        for (int u = 0; u < (P); ++u) cc[u] = col[e + 2*u + half];           \
        _Pragma("unroll")                                                    \
        for (int u = 0; u < (P); ++u) f[u] = tu2[(size_t)cc[u] * 32 + l];    \
        _Pragma("unroll")                                                    \
        for (int u = 0; u < (P); ++u) {                                      \
            a0 += bf2f((unsigned short)(f[u].x & 0xffff));                   \
            a1 += bf2f((unsigned short)(f[u].x >> 16));                      \
            a2 += bf2f((unsigned short)(f[u].y & 0xffff));                   \
            a3 += bf2f((unsigned short)(f[u].y >> 16));                      \
        }                                                                    \
    }
    G128_BATCH(8)
    G128_BATCH(4)
    G128_BATCH(2)
    G128_BATCH(1)
    #undef G128_BATCH
    if (e < b1 && half == 0) {
        int c = col[e];
        uint2 f = tu2[(size_t)c * 32 + l];
        a0 += bf2f((unsigned short)(f.x & 0xffff));
        a1 += bf2f((unsigned short)(f.x >> 16));
        a2 += bf2f((unsigned short)(f.y & 0xffff));
        a3 += bf2f((unsigned short)(f.y >> 16));
    }
    a0 += __shfl_xor(a0, 32);
    a1 += __shfl_xor(a1, 32);
    a2 += __shfl_xor(a2, 32);
    a3 += __shfl_xor(a3, 32);

    if (half == 0) {
        uint2 tv = tu2[(size_t)node * 32 + l];
        a0 += bf2f((unsigned short)(tv.x & 0xffff));
        a1 += bf2f((unsigned short)(tv.x >> 16));
        a2 += bf2f((unsigned short)(tv.y & 0xffff));
        a3 += bf2f((unsigned short)(tv.y >> 16));
        int c0 = 4 * l;
        float4 bi = *(const float4*)&bias[c0];
        float4 gm = *(const float4*)&gam[c0];
        float4 bt = *(const float4*)&bet[c0];
        float4 mv = *(const float4*)&mu[c0];
        float4 vr = *(const float4*)&var[c0];
        float sc0 = gm.x * rsqrtf(vr.x + BN_EPS), sh0 = bt.x - mv.x * sc0;
        float sc1 = gm.y * rsqrtf(vr.y + BN_EPS), sh1 = bt.y - mv.y * sc1;
        float sc2 = gm.z * rsqrtf(vr.z + BN_EPS), sh2 = bt.z - mv.z * sc2;
        float sc3 = gm.w * rsqrtf(vr.w + BN_EPS), sh3 = bt.w - mv.w * sc3;
        float o0 = fmaxf((di * a0 + bi.x) * sc0 + sh0, 0.0f);
        float o1 = fmaxf((di * a1 + bi.y) * sc1 + sh1, 0.0f);
        float o2 = fmaxf((di * a2 + bi.z) * sc2 + sh2, 0.0f);
        float o3 = fmaxf((di * a3 + bi.w) * sc3 + sh3, 0.0f);
        uint2 w;
        w.x = pack2bf(o0, o1);
        w.y = pack2bf(o2, o3);
        ((uint2*)out)[(size_t)node * 32 + l] = w;
    }
}

__global__ __launch_bounds__(256)
void gcn_gather64(const unsigned short* __restrict__ t, unsigned short* __restrict__ out,
                  const int* __restrict__ row_ptr, const int* __restrict__ col,
                  const float* __restrict__ dinv,
                  const float* __restrict__ bias,
                  const float* __restrict__ gam, const float* __restrict__ bet,
                  const float* __restrict__ mu,  const float* __restrict__ var,
                  int Nn) {
    int node = (int)((blockIdx.x * 256 + threadIdx.x) >> 6);
    int lane = threadIdx.x & 63;
    if (node >= Nn) return;
    int half = lane >> 5;
    int l    = lane & 31;
    int b0 = row_ptr[node], b1 = row_ptr[node + 1];
    float di = dinv[node];
    const unsigned int* tu = (const unsigned int*)t;

    float a0 = 0.f, a1 = 0.f;
    int e = b0;
    #define G64_BATCH(P)                                                     \
    for (; e + 2*(P) <= b1; e += 2*(P)) {                                    \
        int cc[P]; unsigned int f[P];                                        \
        _Pragma("unroll")                                                    \
        for (int u = 0; u < (P); ++u) cc[u] = col[e + 2*u + half];           \
        _Pragma("unroll")                                                    \
        for (int u = 0; u < (P); ++u) f[u] = tu[(size_t)cc[u] * 32 + l];     \
        _Pragma("unroll")                                                    \
        for (int u = 0; u < (P); ++u) {                                      \
            a0 += bf2f((unsigned short)(f[u] & 0xffff));                     \
            a1 += bf2f((unsigned short)(f[u] >> 16));                        \
        }                                                                    \
    }
    G64_BATCH(8)
    G64_BATCH(4)
    G64_BATCH(2)
    G64_BATCH(1)
    #undef G64_BATCH
    if (e < b1 && half == 0) {
        int c = col[e];
        unsigned int f = tu[(size_t)c * 32 + l];
        a0 += bf2f((unsigned short)(f & 0xffff));
        a1 += bf2f((unsigned short)(f >> 16));
    }
    a0 += __shfl_xor(a0, 32);
    a1 += __shfl_xor(a1, 32);

    if (half == 0) {
        unsigned int tv = tu[(size_t)node * 32 + l];
        a0 += bf2f((unsigned short)(tv & 0xffff));
        a1 += bf2f((unsigned short)(tv >> 16));
        int c0 = 2 * l, c1 = 2 * l + 1;
        float sc0 = gam[c0] * rsqrtf(var[c0] + BN_EPS), sh0 = bet[c0] - mu[c0] * sc0;
        float sc1 = gam[c1] * rsqrtf(var[c1] + BN_EPS), sh1 = bet[c1] - mu[c1] * sc1;
        float o0 = fmaxf((di * a0 + bias[c0]) * sc0 + sh0, 0.0f);
        float o1 = fmaxf((di * a1 + bias[c1]) * sc1 + sh1, 0.0f);
        ((unsigned int*)out)[(size_t)node * 32 + l] = pack2bf(o0, o1);
    }
}

// ---------------- parallel pool: wave per 64-node chunk, lane = channel ----------------

__global__ __launch_bounds__(256)
void pool_sum_kernel(const unsigned short* __restrict__ h3, const int* __restrict__ batch,
                     float* __restrict__ sums, int Nn) {
    int wid  = (int)((blockIdx.x * 256 + threadIdx.x) >> 6);
    int lane = threadIdx.x & 63;
    int i0 = wid * 64;
    if (i0 >= Nn) return;
    int i1 = i0 + 64; if (i1 > Nn) i1 = Nn;

    float acc = 0.0f;
    int g = batch[i0];
    for (int i = i0; i < i1; ++i) {
        int gi = batch[i];
        if (gi != g) {
            unsafeAtomicAdd(&sums[g * 64 + lane], acc);
            acc = 0.0f;
            g = gi;
        }
        acc += bf2f(h3[(size_t)i * 64 + lane]);
    }
    unsafeAtomicAdd(&sums[g * 64 + lane], acc);
}

// ---------------- MLP head on pooled sums ----------------

__global__ __launch_bounds__(64)
void mlp_kernel(const float* __restrict__ sums, const int* __restrict__ start,
                const float* __restrict__ Wm1, const float* __restrict__ bm1,
                const float* __restrict__ Wm2, const float* __restrict__ bm2,
                float* __restrict__ out) {
    int g = blockIdx.x;
    int c = threadIdx.x;  // 64
    float cnt = (float)(start[g + 1] - start[g]);
    float pooled = sums[g * 64 + c] / fmaxf(cnt, 1.0f);
    __shared__ float pl[64];
    __shared__ float zl[64];
    pl[c] = pooled;
    __syncthreads();
    float z = bm1[c];
    for (int j = 0; j < 64; ++j) z = fmaf(pl[j], Wm1[j * 64 + c], z);
    z = fmaxf(z, 0.0f);
    zl[c] = z;
    __syncthreads();
    if (c < 10) {
        float o = bm2[c];
        for (int j = 0; j < 64; ++j) o = fmaf(zl[j], Wm2[j * 10 + c], o);
        out[g * 10 + c] = o;
    }
}

// ---------------- launcher ----------------

static inline int cdiv(int a, int b) { return (a + b - 1) / b; }

extern "C" void kernel_launch(void* const* d_in, const int* in_sizes, int n_in,
                              void* d_out, int out_size, void* d_ws, size_t ws_size,
                              hipStream_t stream) {
    const float* x   = (const float*)d_in[0];
    const int* edge  = (const int*)d_in[1];
    const int* batch = (const int*)d_in[2];
    const float* W1  = (const float*)d_in[3];
    const float* b1  = (const float*)d_in[4];
    const float* W2  = (const float*)d_in[5];
    const float* b2  = (const float*)d_in[6];
    const float* W3  = (const float*)d_in[7];
    const float* b3  = (const float*)d_in[8];
    const float* g1  = (const float*)d_in[9];
    const float* be1 = (const float*)d_in[10];
    const float* m1  = (const float*)d_in[11];
    const float* v1  = (const float*)d_in[12];
    const float* g2  = (const float*)d_in[13];
    const float* be2 = (const float*)d_in[14];
    const float* m2  = (const float*)d_in[15];
    const float* v2  = (const float*)d_in[16];
    const float* g3  = (const float*)d_in[17];
    const float* be3 = (const float*)d_in[18];
    const float* m3  = (const float*)d_in[19];
    const float* v3  = (const float*)d_in[20];
    const float* Wm1 = (const float*)d_in[21];
    const float* bm1 = (const float*)d_in[22];
    const float* Wm2 = (const float*)d_in[23];
    const float* bm2 = (const float*)d_in[24];
    float* outp = (float*)d_out;

    const int Nn = in_sizes[0] / 128;
    const int E  = in_sizes[1] / 2;
    const int G  = 128;
    const int* srcv = edge;
    const int* dstv = edge + E;

    // ws layout (bytes):
    // bufA (Nn*128 bf16) | bufB (Nn*128 bf16) | dinv (Nn f32) | col (E int)
    // | bkt (256*BCAP int) | row_ptr (Nn+1) | start (G+1) | sums (G*64 f32)
    // | cursor(256) | bucketBase(256)
    char* wsb = (char*)d_ws;
    unsigned short* bufA = (unsigned short*)wsb;
    unsigned short* bufB = bufA + (size_t)Nn * 128;
    float* dinv    = (float*)(bufB + (size_t)Nn * 128);
    int*   col     = (int*)(dinv + Nn);
    int*   bkt     = col + E;
    int*   row_ptr = bkt + (size_t)256 * BCAP;
    int*   start   = row_ptr + (Nn + 1);
    float* sums    = (float*)(start + (G + 1));
    int*   cursor     = (int*)(sums + G * 64);
    int*   bucketBase = cursor + 256;

    const int nbkt = cdiv(Nn, 512);

    // ---- CSR build ----
    hipMemsetAsync(cursor, 0, 256 * sizeof(int), stream);
    bucketA_kernel<<<cdiv(E, 4096), 256, 0, stream>>>(srcv, dstv, cursor, bkt, E);
    scanB_kernel<<<1, 256, 0, stream>>>(cursor, bucketBase, row_ptr, sums, E, Nn, G);
    orderB_kernel<<<nbkt, 256, 0, stream>>>(bkt, cursor, bucketBase, row_ptr, dinv, col,
                                            batch, start, Nn, G);

    // ---- layer 1: t' = dinv*(x @ W1); gather -> bufB ----
    gemm_mfma<128, 128, true><<<cdiv(Nn, 64), 256, 0, stream>>>(x, W1, dinv, bufA, Nn);
    gcn_gather128<<<cdiv(Nn, 4), 256, 0, stream>>>(bufA, bufB, row_ptr, col, dinv,
                                                   b1, g1, be1, m1, v1, Nn);

    // ---- layer 2 ----
    gemm_mfma<128, 64, false><<<cdiv(Nn, 64), 256, 0, stream>>>(bufB, W2, dinv, bufA, Nn);
    gcn_gather64<<<cdiv(Nn, 4), 256, 0, stream>>>(bufA, bufB, row_ptr, col, dinv,
                                                  b2, g2, be2, m2, v2, Nn);

    // ---- layer 3 ----
    gemm_mfma<64, 64, false><<<cdiv(Nn, 64), 256, 0, stream>>>(bufB, W3, dinv, bufA, Nn);
    gcn_gather64<<<cdiv(Nn, 4), 256, 0, stream>>>(bufA, bufB, row_ptr, col, dinv,
                                                  b3, g3, be3, m3, v3, Nn);

    // ---- pool + MLP ----
    pool_sum_kernel<<<cdiv(Nn, 256), 256, 0, stream>>>(bufB, batch, sums, Nn);
    mlp_kernel<<<G, 64, 0, stream>>>(sums, start, Wm1, bm1, Wm2, bm2, outp);
}

// Round 18
// 319.894 us; speedup vs baseline: 1.3090x; 1.0017x over previous
//
#include <hip/hip_runtime.h>
#include <math.h>

#define BN_EPS 1e-5f
#define BCAP 12544   // per-bucket edge capacity (expected ~6250 for uniform dsts)

using bf16x8 = __attribute__((ext_vector_type(8))) short;
using f32x4  = __attribute__((ext_vector_type(4))) float;

#define SEL_LO 0x00003F80u   // bf16 pair (lo=1.0, hi=0.0)
#define SEL_HI 0x3F800000u   // bf16 pair (lo=0.0, hi=1.0)

// acc += bf16(lo|hi selected) of packed pair f  (exact: *1.0 / *0.0, f32 accumulate)
__device__ __forceinline__ void dot2acc(float& acc, unsigned int f, unsigned int sel) {
    asm("v_dot2_f32_bf16 %0, %1, %2, %0" : "+v"(acc) : "v"(f), "v"(sel));
}

// ---------------- bf16 helpers (RNE) ----------------

__device__ __forceinline__ float bf2f(unsigned short u) {
    union { unsigned int i; float f; } v; v.i = ((unsigned int)u) << 16; return v.f;
}
__device__ __forceinline__ unsigned short f2bf(float f) {
    union { float f; unsigned int i; } v; v.f = f;
    unsigned int lsb = (v.i >> 16) & 1u;
    v.i += 0x7fffu + lsb;
    return (unsigned short)(v.i >> 16);
}
__device__ __forceinline__ unsigned int pack2bf(float a, float b) {
    return (unsigned int)f2bf(a) | ((unsigned int)f2bf(b) << 16);
}

// ---------------- CSR build (2-kernel hierarchical) ----------------

__global__ __launch_bounds__(256)
void bucketA_kernel(const int* __restrict__ srcv, const int* __restrict__ dstv,
                    int* __restrict__ cursor, int* __restrict__ bkt, int E) {
    __shared__ int hist[256], base[256], lcur[256];
    int tid = threadIdx.x;
    hist[tid] = 0; lcur[tid] = 0;
    __syncthreads();
    int e0 = blockIdx.x * 4096;
    int nmax = E - e0; if (nmax > 4096) nmax = 4096;

    #pragma unroll
    for (int u = 0; u < 16; ++u) {
        int idx = u * 256 + tid;
        if (idx < nmax) atomicAdd(&hist[dstv[e0 + idx] >> 9], 1);
    }
    __syncthreads();
    if (hist[tid] > 0) base[tid] = atomicAdd(&cursor[tid], hist[tid]);
    __syncthreads();
    #pragma unroll
    for (int u = 0; u < 16; ++u) {
        int idx = u * 256 + tid;
        if (idx < nmax) {
            int e = e0 + idx;
            int d = dstv[e], s = srcv[e];
            int b = d >> 9;
            int dl = d & 511;
            int slot = base[b] + atomicAdd(&lcur[b], 1);
            if (slot < BCAP)
                bkt[b * BCAP + slot] = s | (dl << 17);
        }
    }
}

__global__ void scanB_kernel(const int* __restrict__ cursor, int* __restrict__ bucketBase,
                             int* __restrict__ row_ptr, float* __restrict__ sums,
                             int E, int Nn, int G) {
    __shared__ int s[256];
    int t = threadIdx.x;
    int v = cursor[t];
    s[t] = v;
    __syncthreads();
    for (int off = 1; off < 256; off <<= 1) {
        int add = (t >= off) ? s[t - off] : 0;
        __syncthreads();
        s[t] += add;
        __syncthreads();
    }
    bucketBase[t] = s[t] - v;
    if (t == 0) row_ptr[Nn] = E;
    for (int i = t; i < G * 64; i += 256) sums[i] = 0.0f;
}

__global__ __launch_bounds__(256)
void orderB_kernel(const int* __restrict__ bkt, const int* __restrict__ cursor,
                   const int* __restrict__ bucketBase,
                   int* __restrict__ row_ptr, float* __restrict__ dinv, int* __restrict__ col,
                   const int* __restrict__ batch, int* __restrict__ start,
                   int Nn, int G) {
    __shared__ int hist[512];
    __shared__ int scan_s[256];
    int b = blockIdx.x;
    int lo = b << 9;
    if (lo >= Nn) return;
    int hi = lo + 512; if (hi > Nn) hi = Nn;
    int cnt = cursor[b];
    int g0 = b * BCAP;
    int c0 = bucketBase[b];
    int tid = threadIdx.x;
    hist[tid] = 0; hist[tid + 256] = 0;
    __syncthreads();
    for (int i = tid; i < cnt; i += 256)
        atomicAdd(&hist[(((unsigned int)bkt[g0 + i]) >> 17) & 511], 1);
    __syncthreads();
    int a0 = hist[2 * tid], a1 = hist[2 * tid + 1];
    int n0 = lo + 2 * tid, n1 = n0 + 1;
    if (n0 < Nn) dinv[n0] = rsqrtf((float)a0 + 1.0f);
    if (n1 < Nn) dinv[n1] = rsqrtf((float)a1 + 1.0f);
    int pairsum = a0 + a1;
    scan_s[tid] = pairsum;
    __syncthreads();
    for (int off = 1; off < 256; off <<= 1) {
        int add = (tid >= off) ? scan_s[tid - off] : 0;
        __syncthreads();
        scan_s[tid] += add;
        __syncthreads();
    }
    int excl = scan_s[tid] - pairsum;
    __syncthreads();
    if (n0 < Nn) row_ptr[n0] = c0 + excl;
    if (n1 < Nn) row_ptr[n1] = c0 + excl + a0;
    hist[2 * tid] = excl;
    hist[2 * tid + 1] = excl + a0;
    __syncthreads();
    for (int i = tid; i < cnt; i += 256) {
        int en = bkt[g0 + i];
        int dl = (((unsigned int)en) >> 17) & 511;
        int slot = atomicAdd(&hist[dl], 1);
        col[c0 + slot] = en & 0x1ffff;
    }
    for (int i = lo + tid; i < hi; i += 256) {
        int bb = batch[i];
        if (i == 0) {
            for (int g = 0; g <= bb; ++g) start[g] = 0;
        } else {
            int p = batch[i - 1];
            for (int g = p + 1; g <= bb; ++g) start[g] = i;
        }
        if (i == Nn - 1) {
            for (int g = bb + 1; g <= G; ++g) start[g] = Nn;
        }
    }
}

// ---------------- MFMA GEMM: C[M,N](bf16) = dinv[row] * (A[M,K] @ W[K,N]) ----------------

template<int K, int N, bool AF32>
__global__ __launch_bounds__(256)
void gemm_mfma(const void* __restrict__ Ap, const float* __restrict__ Wf,
               const float* __restrict__ dinv, unsigned short* __restrict__ C, int M) {
    constexpr int KF = K / 32;
    constexpr int NF = N / 16;
    __shared__ __align__(16) unsigned short ldsW[KF * NF * 64 * 8];

    for (int c = threadIdx.x; c < K * N / 8; c += 256) {
        int e0 = c * 8;
        int k = e0 / N, n0 = e0 % N;
        const float4* wp = (const float4*)&Wf[e0];
        float4 v0 = wp[0], v1 = wp[1];
        unsigned short w[8];
        w[0] = f2bf(v0.x); w[1] = f2bf(v0.y); w[2] = f2bf(v0.z); w[3] = f2bf(v0.w);
        w[4] = f2bf(v1.x); w[5] = f2bf(v1.y); w[6] = f2bf(v1.z); w[7] = f2bf(v1.w);
        int j    = k & 7;
        int lhi  = ((k & 31) >> 3) << 4;
        int fbase = (k >> 5) * NF;
        #pragma unroll
        for (int u = 0; u < 8; ++u) {
            int n = n0 + u;
            int f = fbase + (n >> 4);
            int l = lhi | (n & 15);
            ldsW[(f * 64 + l) * 8 + j] = w[u];
        }
    }
    __syncthreads();

    const int wave = threadIdx.x >> 6;
    const int lane = threadIdx.x & 63;
    const int r0   = blockIdx.x * 64 + wave * 16;

    int arow = r0 + (lane & 15);
    if (arow >= M) arow = M - 1;
    const int kc0 = (lane >> 4) * 8;
    bf16x8 af[KF];
    #pragma unroll
    for (int k = 0; k < KF; ++k) {
        if constexpr (AF32) {
            const float* A = (const float*)Ap;
            const float4* p = (const float4*)&A[(size_t)arow * K + k * 32 + kc0];
            float4 u0 = p[0], u1 = p[1];
            unsigned int q0 = pack2bf(u0.x, u0.y), q1 = pack2bf(u0.z, u0.w);
            unsigned int q2 = pack2bf(u1.x, u1.y), q3 = pack2bf(u1.z, u1.w);
            bf16x8 a;
            a[0] = (short)(q0 & 0xffff); a[1] = (short)(q0 >> 16);
            a[2] = (short)(q1 & 0xffff); a[3] = (short)(q1 >> 16);
            a[4] = (short)(q2 & 0xffff); a[5] = (short)(q2 >> 16);
            a[6] = (short)(q3 & 0xffff); a[7] = (short)(q3 >> 16);
            af[k] = a;
        } else {
            const unsigned short* A = (const unsigned short*)Ap;
            af[k] = *(const bf16x8*)&A[(size_t)arow * K + k * 32 + kc0];
        }
    }

    const int colb = lane & 15;
    const int rsub = (lane >> 4) * 4;
    float dv[4];
    #pragma unroll
    for (int j = 0; j < 4; ++j) {
        int row = r0 + rsub + j;
        dv[j] = (row < M) ? dinv[row] : 0.0f;
    }
    #pragma unroll
    for (int n = 0; n < NF; ++n) {
        f32x4 acc = {0.f, 0.f, 0.f, 0.f};
        #pragma unroll
        for (int k = 0; k < KF; ++k) {
            bf16x8 bf = *(const bf16x8*)&ldsW[((k * NF + n) * 64 + lane) * 8];
            acc = __builtin_amdgcn_mfma_f32_16x16x32_bf16(af[k], bf, acc, 0, 0, 0);
        }
        int col = n * 16 + colb;
        #pragma unroll
        for (int j = 0; j < 4; ++j) {
            int row = r0 + rsub + j;
            if (row < M) C[(size_t)row * N + col] = f2bf(acc[j] * dv[j]);
        }
    }
}

// ---------------- fused gather + bias + BN + ReLU (dual-edge half-wave, dot2 accumulate) ----

__global__ __launch_bounds__(256)
void gcn_gather128(const unsigned short* __restrict__ t, unsigned short* __restrict__ out,
                   const int* __restrict__ row_ptr, const int* __restrict__ col,
                   const float* __restrict__ dinv,
                   const float* __restrict__ bias,
                   const float* __restrict__ gam, const float* __restrict__ bet,
                   const float* __restrict__ mu,  const float* __restrict__ var,
                   int Nn) {
    int node = (int)((blockIdx.x * 256 + threadIdx.x) >> 6);
    int lane = threadIdx.x & 63;
    if (node >= Nn) return;
    int half = lane >> 5;
    int l    = lane & 31;
    int b0 = row_ptr[node], b1 = row_ptr[node + 1];
    float di = dinv[node];
    const uint2* tu2 = (const uint2*)t;
    const unsigned int selLo = SEL_LO, selHi = SEL_HI;

    float a0 = 0.f, a1 = 0.f, a2 = 0.f, a3 = 0.f;
    int e = b0;
    #define G128_BATCH(P)                                                    \
    for (; e + 2*(P) <= b1; e += 2*(P)) {                                    \
        int cc[P]; uint2 f[P];                                               \
        _Pragma("unroll")                                                    \
        for (int u = 0; u < (P); ++u) cc[u] = col[e + 2*u + half];           \
        _Pragma("unroll")                                                    \
        for (int u = 0; u < (P); ++u) f[u] = tu2[(size_t)cc[u] * 32 + l];    \
        _Pragma("unroll")                                                    \
        for (int u = 0; u < (P); ++u) {                                      \
            dot2acc(a0, f[u].x, selLo);                                      \
            dot2acc(a1, f[u].x, selHi);                                      \
            dot2acc(a2, f[u].y, selLo);                                      \
            dot2acc(a3, f[u].y, selHi);                                      \
        }                                                                    \
    }
    G128_BATCH(8)
    G128_BATCH(4)
    G128_BATCH(2)
    G128_BATCH(1)
    #undef G128_BATCH
    if (e < b1 && half == 0) {
        int c = col[e];
        uint2 f = tu2[(size_t)c * 32 + l];
        dot2acc(a0, f.x, selLo);
        dot2acc(a1, f.x, selHi);
        dot2acc(a2, f.y, selLo);
        dot2acc(a3, f.y, selHi);
    }
    a0 += __shfl_xor(a0, 32);
    a1 += __shfl_xor(a1, 32);
    a2 += __shfl_xor(a2, 32);
    a3 += __shfl_xor(a3, 32);

    if (half == 0) {
        uint2 tv = tu2[(size_t)node * 32 + l];
        a0 += bf2f((unsigned short)(tv.x & 0xffff));
        a1 += bf2f((unsigned short)(tv.x >> 16));
        a2 += bf2f((unsigned short)(tv.y & 0xffff));
        a3 += bf2f((unsigned short)(tv.y >> 16));
        int c0 = 4 * l;
        float4 bi = *(const float4*)&bias[c0];
        float4 gm = *(const float4*)&gam[c0];
        float4 bt = *(const float4*)&bet[c0];
        float4 mv = *(const float4*)&mu[c0];
        float4 vr = *(const float4*)&var[c0];
        float sc0 = gm.x * rsqrtf(vr.x + BN_EPS), sh0 = bt.x - mv.x * sc0;
        float sc1 = gm.y * rsqrtf(vr.y + BN_EPS), sh1 = bt.y - mv.y * sc1;
        float sc2 = gm.z * rsqrtf(vr.z + BN_EPS), sh2 = bt.z - mv.z * sc2;
        float sc3 = gm.w * rsqrtf(vr.w + BN_EPS), sh3 = bt.w - mv.w * sc3;
        float o0 = fmaxf((di * a0 + bi.x) * sc0 + sh0, 0.0f);
        float o1 = fmaxf((di * a1 + bi.y) * sc1 + sh1, 0.0f);
        float o2 = fmaxf((di * a2 + bi.z) * sc2 + sh2, 0.0f);
        float o3 = fmaxf((di * a3 + bi.w) * sc3 + sh3, 0.0f);
        uint2 w;
        w.x = pack2bf(o0, o1);
        w.y = pack2bf(o2, o3);
        ((uint2*)out)[(size_t)node * 32 + l] = w;
    }
}

__global__ __launch_bounds__(256)
void gcn_gather64(const unsigned short* __restrict__ t, unsigned short* __restrict__ out,
                  const int* __restrict__ row_ptr, const int* __restrict__ col,
                  const float* __restrict__ dinv,
                  const float* __restrict__ bias,
                  const float* __restrict__ gam, const float* __restrict__ bet,
                  const float* __restrict__ mu,  const float* __restrict__ var,
                  int Nn) {
    int node = (int)((blockIdx.x * 256 + threadIdx.x) >> 6);
    int lane = threadIdx.x & 63;
    if (node >= Nn) return;
    int half = lane >> 5;
    int l    = lane & 31;
    int b0 = row_ptr[node], b1 = row_ptr[node + 1];
    float di = dinv[node];
    const unsigned int* tu = (const unsigned int*)t;
    const unsigned int selLo = SEL_LO, selHi = SEL_HI;

    float a0 = 0.f, a1 = 0.f;
    int e = b0;
    #define G64_BATCH(P)                                                     \
    for (; e + 2*(P) <= b1; e += 2*(P)) {                                    \
        int cc[P]; unsigned int f[P];                                        \
        _Pragma("unroll")                                                    \
        for (int u = 0; u < (P); ++u) cc[u] = col[e + 2*u + half];           \
        _Pragma("unroll")                                                    \
        for (int u = 0; u < (P); ++u) f[u] = tu[(size_t)cc[u] * 32 + l];     \
        _Pragma("unroll")                                                    \
        for (int u = 0; u < (P); ++u) {                                      \
            dot2acc(a0, f[u], selLo);                                        \
            dot2acc(a1, f[u], selHi);                                        \
        }                                                                    \
    }
    G64_BATCH(8)
    G64_BATCH(4)
    G64_BATCH(2)
    G64_BATCH(1)
    #undef G64_BATCH
    if (e < b1 && half == 0) {
        int c = col[e];
        unsigned int f = tu[(size_t)c * 32 + l];
        dot2acc(a0, f, selLo);
        dot2acc(a1, f, selHi);
    }
    a0 += __shfl_xor(a0, 32);
    a1 += __shfl_xor(a1, 32);

    if (half == 0) {
        unsigned int tv = tu[(size_t)node * 32 + l];
        a0 += bf2f((unsigned short)(tv & 0xffff));
        a1 += bf2f((unsigned short)(tv >> 16));
        int c0 = 2 * l, c1 = 2 * l + 1;
        float sc0 = gam[c0] * rsqrtf(var[c0] + BN_EPS), sh0 = bet[c0] - mu[c0] * sc0;
        float sc1 = gam[c1] * rsqrtf(var[c1] + BN_EPS), sh1 = bet[c1] - mu[c1] * sc1;
        float o0 = fmaxf((di * a0 + bias[c0]) * sc0 + sh0, 0.0f);
        float o1 = fmaxf((di * a1 + bias[c1]) * sc1 + sh1, 0.0f);
        ((unsigned int*)out)[(size_t)node * 32 + l] = pack2bf(o0, o1);
    }
}

// ---------------- parallel pool: wave per 64-node chunk, lane = channel ----------------

__global__ __launch_bounds__(256)
void pool_sum_kernel(const unsigned short* __restrict__ h3, const int* __restrict__ batch,
                     float* __restrict__ sums, int Nn) {
    int wid  = (int)((blockIdx.x * 256 + threadIdx.x) >> 6);
    int lane = threadIdx.x & 63;
    int i0 = wid * 64;
    if (i0 >= Nn) return;
    int i1 = i0 + 64; if (i1 > Nn) i1 = Nn;

    float acc = 0.0f;
    int g = batch[i0];
    for (int i = i0; i < i1; ++i) {
        int gi = batch[i];
        if (gi != g) {
            unsafeAtomicAdd(&sums[g * 64 + lane], acc);
            acc = 0.0f;
            g = gi;
        }
        acc += bf2f(h3[(size_t)i * 64 + lane]);
    }
    unsafeAtomicAdd(&sums[g * 64 + lane], acc);
}

// ---------------- MLP head on pooled sums ----------------

__global__ __launch_bounds__(64)
void mlp_kernel(const float* __restrict__ sums, const int* __restrict__ start,
                const float* __restrict__ Wm1, const float* __restrict__ bm1,
                const float* __restrict__ Wm2, const float* __restrict__ bm2,
                float* __restrict__ out) {
    int g = blockIdx.x;
    int c = threadIdx.x;  // 64
    float cnt = (float)(start[g + 1] - start[g]);
    float pooled = sums[g * 64 + c] / fmaxf(cnt, 1.0f);
    __shared__ float pl[64];
    __shared__ float zl[64];
    pl[c] = pooled;
    __syncthreads();
    float z = bm1[c];
    for (int j = 0; j < 64; ++j) z = fmaf(pl[j], Wm1[j * 64 + c], z);
    z = fmaxf(z, 0.0f);
    zl[c] = z;
    __syncthreads();
    if (c < 10) {
        float o = bm2[c];
        for (int j = 0; j < 64; ++j) o = fmaf(zl[j], Wm2[j * 10 + c], o);
        out[g * 10 + c] = o;
    }
}

// ---------------- launcher ----------------

static inline int cdiv(int a, int b) { return (a + b - 1) / b; }

extern "C" void kernel_launch(void* const* d_in, const int* in_sizes, int n_in,
                              void* d_out, int out_size, void* d_ws, size_t ws_size,
                              hipStream_t stream) {
    const float* x   = (const float*)d_in[0];
    const int* edge  = (const int*)d_in[1];
    const int* batch = (const int*)d_in[2];
    const float* W1  = (const float*)d_in[3];
    const float* b1  = (const float*)d_in[4];
    const float* W2  = (const float*)d_in[5];
    const float* b2  = (const float*)d_in[6];
    const float* W3  = (const float*)d_in[7];
    const float* b3  = (const float*)d_in[8];
    const float* g1  = (const float*)d_in[9];
    const float* be1 = (const float*)d_in[10];
    const float* m1  = (const float*)d_in[11];
    const float* v1  = (const float*)d_in[12];
    const float* g2  = (const float*)d_in[13];
    const float* be2 = (const float*)d_in[14];
    const float* m2  = (const float*)d_in[15];
    const float* v2  = (const float*)d_in[16];
    const float* g3  = (const float*)d_in[17];
    const float* be3 = (const float*)d_in[18];
    const float* m3  = (const float*)d_in[19];
    const float* v3  = (const float*)d_in[20];
    const float* Wm1 = (const float*)d_in[21];
    const float* bm1 = (const float*)d_in[22];
    const float* Wm2 = (const float*)d_in[23];
    const float* bm2 = (const float*)d_in[24];
    float* outp = (float*)d_out;

    const int Nn = in_sizes[0] / 128;
    const int E  = in_sizes[1] / 2;
    const int G  = 128;
    const int* srcv = edge;
    const int* dstv = edge + E;

    char* wsb = (char*)d_ws;
    unsigned short* bufA = (unsigned short*)wsb;
    unsigned short* bufB = bufA + (size_t)Nn * 128;
    float* dinv    = (float*)(bufB + (size_t)Nn * 128);
    int*   col     = (int*)(dinv + Nn);
    int*   bkt     = col + E;
    int*   row_ptr = bkt + (size_t)256 * BCAP;
    int*   start   = row_ptr + (Nn + 1);
    float* sums    = (float*)(start + (G + 1));
    int*   cursor     = (int*)(sums + G * 64);
    int*   bucketBase = cursor + 256;

    const int nbkt = cdiv(Nn, 512);

    // ---- CSR build ----
    hipMemsetAsync(cursor, 0, 256 * sizeof(int), stream);
    bucketA_kernel<<<cdiv(E, 4096), 256, 0, stream>>>(srcv, dstv, cursor, bkt, E);
    scanB_kernel<<<1, 256, 0, stream>>>(cursor, bucketBase, row_ptr, sums, E, Nn, G);
    orderB_kernel<<<nbkt, 256, 0, stream>>>(bkt, cursor, bucketBase, row_ptr, dinv, col,
                                            batch, start, Nn, G);

    // ---- layer 1: t' = dinv*(x @ W1); gather -> bufB ----
    gemm_mfma<128, 128, true><<<cdiv(Nn, 64), 256, 0, stream>>>(x, W1, dinv, bufA, Nn);
    gcn_gather128<<<cdiv(Nn, 4), 256, 0, stream>>>(bufA, bufB, row_ptr, col, dinv,
                                                   b1, g1, be1, m1, v1, Nn);

    // ---- layer 2 ----
    gemm_mfma<128, 64, false><<<cdiv(Nn, 64), 256, 0, stream>>>(bufB, W2, dinv, bufA, Nn);
    gcn_gather64<<<cdiv(Nn, 4), 256, 0, stream>>>(bufA, bufB, row_ptr, col, dinv,
                                                  b2, g2, be2, m2, v2, Nn);

    // ---- layer 3 ----
    gemm_mfma<64, 64, false><<<cdiv(Nn, 64), 256, 0, stream>>>(bufB, W3, dinv, bufA, Nn);
    gcn_gather64<<<cdiv(Nn, 4), 256, 0, stream>>>(bufA, bufB, row_ptr, col, dinv,
                                                  b3, g3, be3, m3, v3, Nn);

    // ---- pool + MLP ----
    pool_sum_kernel<<<cdiv(Nn, 256), 256, 0, stream>>>(bufB, batch, sums, Nn);
    mlp_kernel<<<G, 64, 0, stream>>>(sums, start, Wm1, bm1, Wm2, bm2, outp);
}